// Round 8
// baseline (133.417 us; speedup 1.0000x reference)
//
#include <hip/hip_runtime.h>
#include <hip/hip_bf16.h>

// Problem constants
#define N_G 32
#define E_N 512
#define IN_D 128
#define OUT_D 64
#define NT 3
#define Q_D 128

// Workspace layout (float elements)
//  w_src  [3][32][128]   @ 0
//  w_dst  [3][32][128]   @ 12288
//  s_src  [3][32][512]   @ 24576
//  s_dst  [3][32][512]   @ 73728
//  invsum [32][512]      @ 139264
//  hTg    [32][64][512]  @ 155648  (bf16, TRANSPOSED: [n][d][e], 1048576 ushorts)
//  W2T    [64][128]      @ 679936  (bf16, 8192 ushorts) W[2]^T
//  adj2   [32][512][64]  @ 684032  (ushort 2-bit codes: word u holds j=u+64b at bits 2b)
#define WS_WSRC 0
#define WS_WDST 12288
#define WS_SSRC 24576
#define WS_SDST 73728
#define WS_RINV 139264
#define WS_H    155648
#define WS_W2T  679936
#define WS_ADJ2 684032

typedef const float* fp;
typedef __attribute__((ext_vector_type(8))) short short8x;   // 8 bf16 (A/B frag)
typedef __attribute__((ext_vector_type(4))) float float4x;   // C/D frag

static __device__ inline ushort f2bf(float x) {
  __hip_bfloat16 b = __float2bfloat16(x);
  return *(ushort*)&b;
}
static __device__ inline float bf2f(ushort u) {
  return __uint_as_float((uint)u << 16);
}

// ---------------------------------------------------------------------------
// K1: qg = sigmoid(relu(qv@W1)@W2); w_{src,dst}[t,n,i] = sum_d W[t,i,d]*qg*a
// t==2 blocks additionally write W2T (bf16 W[2]^T [d][i]) for k2's B operand.
// ---------------------------------------------------------------------------
__global__ __launch_bounds__(128) void k1_qgate(fp qv_g, fp Wt, fp at,
                                                fp W1, fp W2,
                                                float* __restrict__ ws) {
  const int tb = blockIdx.x >> 5;
  const int n  = blockIdx.x & 31;
  __shared__ float qv[128], g1[128], g2[128], gs[64], gd[64];
  const int c = threadIdx.x;

  qv[c] = qv_g[n * Q_D + c];
  __syncthreads();

  float acc = 0.f;
  #pragma unroll 8
  for (int q = 0; q < 128; q++) acc += qv[q] * W1[tb * 16384 + q * 128 + c];
  g1[c] = acc > 0.f ? acc : 0.f;
  __syncthreads();

  acc = 0.f;
  #pragma unroll 8
  for (int q = 0; q < 128; q++) acc += g1[q] * W2[tb * 16384 + q * 128 + c];
  g2[c] = 1.f / (1.f + __expf(-acc));
  __syncthreads();

  if (c < 64) {
    gs[c] = g2[c] * at[tb * 128 + c];
    gd[c] = g2[64 + c] * at[tb * 128 + 64 + c];
  }
  __syncthreads();

  float as = 0.f, ad = 0.f;
  #pragma unroll 8
  for (int d = 0; d < 64; d++) {
    float w = Wt[tb * 8192 + c * 64 + d];
    as += w * gs[d];
    ad += w * gd[d];
  }
  ws[WS_WSRC + tb * 4096 + n * 128 + c] = as;
  ws[WS_WDST + tb * 4096 + n * 128 + c] = ad;

  // W2T: 8192 ushorts total; 32 t==2 blocks x 128 threads x 2 elems
  if (tb == 2) {
    int f = n * 256 + c * 2;            // even flat index into [d][i]
    int d = f >> 7, i0 = f & 127;
    uint lo = f2bf(Wt[2 * 8192 + i0 * 64 + d]);
    uint hi = f2bf(Wt[2 * 8192 + (i0 + 1) * 64 + d]);
    ((uint*)(ws + WS_W2T))[f >> 1] = lo | (hi << 16);
  }
}

// ---------------------------------------------------------------------------
// K2: h = mask * X@W[2] via MFMA, stored TRANSPOSED hTg[n][d][e] (bf16);
//     s_{src,dst}[t,n,e] = X . w_{src,dst}
// grid 512 (n = b>>4, e-tile 32 = b&15), block 256 = 4 waves.
// Epilogue routes C through a small LDS tile (eT) so global h writes are
// uint4 with full 64-B sector utilization in the [d][e] layout.
// ---------------------------------------------------------------------------
__global__ __launch_bounds__(256) void k2_h_s(fp X, fp mask,
                                              float* __restrict__ ws) {
  const int n  = blockIdx.x >> 4;
  const int e0 = (blockIdx.x & 15) << 5;
  __shared__ ushort A[32 * 136];    // [e][i], stride 136 (272B = 16*17)
  __shared__ ushort BT[64 * 136];   // [d][i]
  __shared__ ushort eT[64 * 40];    // [d][e-local], stride 40 (80B, 16B-mult)
  __shared__ float wv[6 * 128];
  const int t = threadIdx.x;
  ushort* hb = (ushort*)(ws + WS_H);
  const ushort* w2t = (const ushort*)(ws + WS_W2T);

  #pragma unroll
  for (int k = 0; k < 4; k++) {
    int f = t + 256 * k;                 // 0..1023
    int e = f >> 5, iq = f & 31;
    float4 v = *(const float4*)&X[(n * E_N + e0 + e) * IN_D + iq * 4];
    uint2 pk;
    pk.x = (uint)f2bf(v.x) | ((uint)f2bf(v.y) << 16);
    pk.y = (uint)f2bf(v.z) | ((uint)f2bf(v.w) << 16);
    *(uint2*)&A[e * 136 + iq * 4] = pk;
  }
  #pragma unroll
  for (int k = 0; k < 4; k++) {
    int f = t + 256 * k;                 // 0..1023
    int d = f >> 4, iq8 = f & 15;
    *(uint4*)&BT[d * 136 + iq8 * 8] = *(const uint4*)&w2t[d * 128 + iq8 * 8];
  }
  #pragma unroll
  for (int k = 0; k < 3; k++) {
    int idx = t + 256 * k;               // 768
    int row = idx >> 7, i = idx & 127;
    wv[idx] = (row < 3) ? ws[WS_WSRC + row * 4096 + n * 128 + i]
                        : ws[WS_WDST + (row - 3) * 4096 + n * 128 + i];
  }
  __syncthreads();

  const int w = t >> 6, lane = t & 63;
  const int m15 = lane & 15, quad = lane >> 4;
  const int msub = w & 1, dhalf = w >> 1;

  float4x acc2[2];
  acc2[0] = (float4x)(0.f); acc2[1] = (float4x)(0.f);
  #pragma unroll
  for (int ks = 0; ks < 4; ks++) {
    short8x af = *(const short8x*)&A[(msub * 16 + m15) * 136 + ks * 32 + quad * 8];
    #pragma unroll
    for (int dd = 0; dd < 2; dd++) {
      short8x bfv = *(const short8x*)&BT[((dhalf * 2 + dd) * 16 + m15) * 136 + ks * 32 + quad * 8];
      acc2[dd] = __builtin_amdgcn_mfma_f32_16x16x32_bf16(af, bfv, acc2[dd], 0, 0, 0);
    }
  }

  if (t < 192) {
    const int e = t / 6, q = t % 6;
    float acc = 0.f;
    #pragma unroll
    for (int i8 = 0; i8 < 16; i8++) {
      uint4 pk = *(const uint4*)&A[e * 136 + i8 * 8];
      const float* wp = &wv[q * 128 + i8 * 8];
      acc += bf2f((ushort)(pk.x & 0xffff)) * wp[0];
      acc += bf2f((ushort)(pk.x >> 16))    * wp[1];
      acc += bf2f((ushort)(pk.y & 0xffff)) * wp[2];
      acc += bf2f((ushort)(pk.y >> 16))    * wp[3];
      acc += bf2f((ushort)(pk.z & 0xffff)) * wp[4];
      acc += bf2f((ushort)(pk.z >> 16))    * wp[5];
      acc += bf2f((ushort)(pk.w & 0xffff)) * wp[6];
      acc += bf2f((ushort)(pk.w >> 16))    * wp[7];
    }
    if (q < 3) ws[WS_SSRC + q * 16384 + n * 512 + e0 + e] = acc;
    else       ws[WS_SDST + (q - 3) * 16384 + n * 512 + e0 + e] = acc;
  }

  // epilogue: C (e=quad*4+rg row, d=16*dd16+m15 col) * mask -> eT[d][e] bf16
  float mv[4];
  #pragma unroll
  for (int rg = 0; rg < 4; rg++)
    mv[rg] = mask[n * E_N + e0 + msub * 16 + quad * 4 + rg];
  #pragma unroll
  for (int dd = 0; dd < 2; dd++) {
    int dRow = (dhalf * 2 + dd) * 16 + m15;
    #pragma unroll
    for (int rg = 0; rg < 4; rg++) {
      int e = msub * 16 + quad * 4 + rg;
      eT[dRow * 40 + e] = f2bf(acc2[dd][rg] * mv[rg]);
    }
  }
  __syncthreads();

  // hTg[n][d][e0+e]: one uint4 (8 e) per thread, sector-coalesced
  {
    int d = t >> 2, e8 = t & 3;
    *(uint4*)&hb[(n * 64 + d) * 512 + e0 + e8 * 8] =
        *(const uint4*)&eT[d * 40 + e8 * 8];
  }
}

// ---------------------------------------------------------------------------
// K3: per-row softmax denom + 2-bit adj pack (4096 blocks, wave-per-row).
// ---------------------------------------------------------------------------
__global__ __launch_bounds__(256) void k3_rowstats(const int* __restrict__ adj,
                                                   float* __restrict__ ws) {
  const int n  = blockIdx.x >> 7;
  const int ib = blockIdx.x & 127;
  __shared__ float sd[3 * 512];
  const int t = threadIdx.x;
  ushort* adj2 = (ushort*)(ws + WS_ADJ2);

  #pragma unroll
  for (int k = 0; k < 6; k++) {
    int idx = t + 256 * k;
    sd[idx] = ws[WS_SDST + (idx >> 9) * 16384 + n * 512 + (idx & 511)];
  }
  __syncthreads();

  const int wave = t >> 6, lane = t & 63;
  const int i = ib * 4 + wave;
  const float s0 = ws[WS_SSRC + 0 * 16384 + n * 512 + i];
  const float s1 = ws[WS_SSRC + 1 * 16384 + n * 512 + i];
  const float s2 = ws[WS_SSRC + 2 * 16384 + n * 512 + i];
  const int* arow = &adj[(n * E_N + i) * E_N];

  float sum = 0.f;
  uint pack = 0;
  #pragma unroll
  for (int b = 0; b < 8; b++) {
    int j = b * 64 + lane;
    int a = arow[j];
    pack |= (uint)(a & 3) << (2 * b);
    if (a > 0) {
      float s = (a == 1) ? s0 : (a == 2 ? s1 : s2);
      float v = s + sd[(a - 1) * 512 + j];
      v = v > 0.f ? v : 0.2f * v;
      sum += __expf(v);
    }
  }
  #pragma unroll
  for (int off = 32; off >= 1; off >>= 1) sum += __shfl_xor(sum, off, 64);
  if (lane == 0) ws[WS_RINV + n * 512 + i] = 1.f / sum;
  adj2[(n * E_N + i) * 64 + lane] = (ushort)pack;   // 128 B/wave coalesced
}

// ---------------------------------------------------------------------------
// K4: out[n,j,d] = sum_i coef[n,i,j]*h[n,i,d] via MFMA, single pass over i.
// grid 32*16 (n, j-tile 32), block 256 = 4 waves. 4 i-chunks of 128.
// B-fragments loaded DIRECTLY from transposed global hTg (prefetched at
// chunk top; L2-hot, shared by the 16 j-tile blocks of each n). No hT LDS.
// ---------------------------------------------------------------------------
__global__ __launch_bounds__(256) void k4_out(float* __restrict__ ws,
                                              float* __restrict__ out) {
  const int n  = blockIdx.x >> 4;
  const int j0 = (blockIdx.x & 15) << 5;
  __shared__ ushort cT[32 * 136];
  __shared__ ushort aS[128 * 64];   // adj2 tile [i-local][u]
  __shared__ float sdT[3 * 32];
  __shared__ float ssT[3 * 128];
  __shared__ float riT[128];
  const int t = threadIdx.x;
  const ushort* hb = (const ushort*)(ws + WS_H);
  const ushort* adj2 = (const ushort*)(ws + WS_ADJ2);

  if (t < 96) sdT[t] = ws[WS_SDST + (t >> 5) * 16384 + n * 512 + j0 + (t & 31)];

  const int w = t >> 6, lane = t & 63;
  const int m15 = lane & 15, quad = lane >> 4;
  const int msub = w & 1, dhalf = w >> 1;
  const int c   = t & 31;            // j-local col (coef phase)
  const int rpb = t >> 5;            // 0..7 row-pair base
  const int u     = (j0 & 63) + c;   // ushort index within adj2 row
  const int shift = 2 * (j0 >> 6);   // bit position (block-uniform)

  float4x acc[2];
  acc[0] = (float4x)(0.f); acc[1] = (float4x)(0.f);

  for (int it = 0; it < 4; it++) {
    const int i0 = it << 7;

    // B-fragment prefetch: 8 x 16B from global hTg (covers latency over
    // the staging + coef phases below)
    short8x bfr[4][2];
    #pragma unroll
    for (int ks = 0; ks < 4; ks++)
      #pragma unroll
      for (int dd = 0; dd < 2; dd++) {
        int dRow = (dhalf * 2 + dd) * 16 + m15;
        bfr[ks][dd] = *(const short8x*)&hb[(n * 64 + dRow) * 512 + i0 + ks * 32 + quad * 8];
      }

    // adj2 tile: 8192 ushorts = 1024 uint4, coalesced
    #pragma unroll
    for (int k = 0; k < 4; k++) {
      int f = t + 256 * k;               // 0..1023
      int r = f >> 3, c8 = f & 7;
      *(uint4*)&aS[r * 64 + c8 * 8] =
          *(const uint4*)&adj2[(size_t)(n * E_N + i0 + r) * 64 + c8 * 8];
    }
    // riT/ssT: 512 floats
    #pragma unroll
    for (int k = 0; k < 2; k++) {
      int idx = t + 256 * k;
      if (idx < 128) riT[idx] = ws[WS_RINV + n * 512 + i0 + idx];
      else {
        int j2 = idx - 128;
        ssT[j2] = ws[WS_SSRC + (j2 >> 7) * 16384 + n * 512 + i0 + (j2 & 127)];
      }
    }
    __syncthreads();

    // coef -> bf16 pairs -> cT[j][i]; adj codes from LDS aS
    #pragma unroll
    for (int k = 0; k < 8; k++) {
      int r0 = 2 * (rpb + 8 * k);
      uint pack = 0;
      int a = (aS[r0 * 64 + u] >> shift) & 3;
      if (a > 0) {
        float v = ssT[(a - 1) * 128 + r0] + sdT[(a - 1) * 32 + c];
        v = v > 0.f ? v : 0.2f * v;
        pack = f2bf(__expf(v) * riT[r0]);
      }
      a = (aS[(r0 + 1) * 64 + u] >> shift) & 3;
      if (a > 0) {
        float v = ssT[(a - 1) * 128 + r0 + 1] + sdT[(a - 1) * 32 + c];
        v = v > 0.f ? v : 0.2f * v;
        pack |= (uint)f2bf(__expf(v) * riT[r0 + 1]) << 16;
      }
      *(uint*)&cT[c * 136 + r0] = pack;
    }
    __syncthreads();

    #pragma unroll
    for (int ks = 0; ks < 4; ks++) {
      short8x af = *(const short8x*)&cT[(msub * 16 + m15) * 136 + ks * 32 + quad * 8];
      #pragma unroll
      for (int dd = 0; dd < 2; dd++)
        acc[dd] = __builtin_amdgcn_mfma_f32_16x16x32_bf16(af, bfr[ks][dd], acc[dd], 0, 0, 0);
    }
    __syncthreads();
  }

  #pragma unroll
  for (int dd = 0; dd < 2; dd++)
    #pragma unroll
    for (int rg = 0; rg < 4; rg++) {
      int j = j0 + msub * 16 + quad * 4 + rg;
      out[(n * E_N + j) * 64 + (dhalf * 2 + dd) * 16 + m15] = acc[dd][rg];
    }
}

extern "C" void kernel_launch(void* const* d_in, const int* in_sizes, int n_in,
                              void* d_out, int out_size, void* d_ws, size_t ws_size,
                              hipStream_t stream) {
  fp input_state  = (fp)d_in[0];
  const int* adj  = (const int*)d_in[1];
  fp query_vec    = (fp)d_in[2];
  fp node_mask    = (fp)d_in[3];
  fp W_type       = (fp)d_in[4];
  fp a_type       = (fp)d_in[5];
  fp qattn_W1     = (fp)d_in[6];
  fp qattn_W2     = (fp)d_in[7];
  float* out = (float*)d_out;
  float* ws  = (float*)d_ws;

  k1_qgate<<<96, 128, 0, stream>>>(query_vec, W_type, a_type, qattn_W1, qattn_W2, ws);
  k2_h_s<<<512, 256, 0, stream>>>(input_state, node_mask, ws);
  k3_rowstats<<<32 * 128, 256, 0, stream>>>(adj, ws);
  k4_out<<<32 * 16, 256, 0, stream>>>(ws, out);
}

// Round 9
// 131.029 us; speedup vs baseline: 1.0182x; 1.0182x over previous
//
#include <hip/hip_runtime.h>
#include <hip/hip_bf16.h>

// Problem constants
#define N_G 32
#define E_N 512
#define IN_D 128
#define OUT_D 64
#define NT 3
#define Q_D 128

// Workspace layout (float elements)
//  w_src  [3][32][128]   @ 0
//  w_dst  [3][32][128]   @ 12288
//  s_src  [3][32][512]   @ 24576
//  s_dst  [3][32][512]   @ 73728
//  invsum [32][512]      @ 139264
//  hTg    [32][64][512]  @ 155648  (bf16, TRANSPOSED: [n][d][e], 1048576 ushorts)
//  W2T    [64][128]      @ 679936  (bf16, 8192 ushorts) W[2]^T
//  adj2   [32][512][64]  @ 684032  (ushort 2-bit codes: word u holds j=u+64b at bits 2b)
#define WS_WSRC 0
#define WS_WDST 12288
#define WS_SSRC 24576
#define WS_SDST 73728
#define WS_RINV 139264
#define WS_H    155648
#define WS_W2T  679936
#define WS_ADJ2 684032

typedef const float* fp;
typedef __attribute__((ext_vector_type(8))) short short8x;   // 8 bf16 (A/B frag)
typedef __attribute__((ext_vector_type(4))) float float4x;   // C/D frag

static __device__ inline ushort f2bf(float x) {
  __hip_bfloat16 b = __float2bfloat16(x);
  return *(ushort*)&b;
}
static __device__ inline float bf2f(ushort u) {
  return __uint_as_float((uint)u << 16);
}

// ---------------------------------------------------------------------------
// K1: qg = sigmoid(relu(qv@W1)@W2); w_{src,dst}[t,n,i] = sum_d W[t,i,d]*qg*a
// t==2 blocks additionally write W2T (bf16 W[2]^T [d][i]) for k2's B operand.
// ---------------------------------------------------------------------------
__global__ __launch_bounds__(128) void k1_qgate(fp qv_g, fp Wt, fp at,
                                                fp W1, fp W2,
                                                float* __restrict__ ws) {
  const int tb = blockIdx.x >> 5;
  const int n  = blockIdx.x & 31;
  __shared__ float qv[128], g1[128], g2[128], gs[64], gd[64];
  const int c = threadIdx.x;

  qv[c] = qv_g[n * Q_D + c];
  __syncthreads();

  float acc = 0.f;
  #pragma unroll 8
  for (int q = 0; q < 128; q++) acc += qv[q] * W1[tb * 16384 + q * 128 + c];
  g1[c] = acc > 0.f ? acc : 0.f;
  __syncthreads();

  acc = 0.f;
  #pragma unroll 8
  for (int q = 0; q < 128; q++) acc += g1[q] * W2[tb * 16384 + q * 128 + c];
  g2[c] = 1.f / (1.f + __expf(-acc));
  __syncthreads();

  if (c < 64) {
    gs[c] = g2[c] * at[tb * 128 + c];
    gd[c] = g2[64 + c] * at[tb * 128 + 64 + c];
  }
  __syncthreads();

  float as = 0.f, ad = 0.f;
  #pragma unroll 8
  for (int d = 0; d < 64; d++) {
    float w = Wt[tb * 8192 + c * 64 + d];
    as += w * gs[d];
    ad += w * gd[d];
  }
  ws[WS_WSRC + tb * 4096 + n * 128 + c] = as;
  ws[WS_WDST + tb * 4096 + n * 128 + c] = ad;

  // W2T: 8192 ushorts total; 32 t==2 blocks x 128 threads x 2 elems
  if (tb == 2) {
    int f = n * 256 + c * 2;            // even flat index into [d][i]
    int d = f >> 7, i0 = f & 127;
    uint lo = f2bf(Wt[2 * 8192 + i0 * 64 + d]);
    uint hi = f2bf(Wt[2 * 8192 + (i0 + 1) * 64 + d]);
    ((uint*)(ws + WS_W2T))[f >> 1] = lo | (hi << 16);
  }
}

// ---------------------------------------------------------------------------
// K2: h = mask * X@W[2] via MFMA, stored TRANSPOSED hTg[n][d][e] (bf16);
//     s_{src,dst}[t,n,e] = X . w_{src,dst}
// grid 512 (n = b>>4, e-tile 32 = b&15), block 256 = 4 waves.
// ---------------------------------------------------------------------------
__global__ __launch_bounds__(256) void k2_h_s(fp X, fp mask,
                                              float* __restrict__ ws) {
  const int n  = blockIdx.x >> 4;
  const int e0 = (blockIdx.x & 15) << 5;
  __shared__ ushort A[32 * 136];    // [e][i], stride 136 (272B = 16*17)
  __shared__ ushort BT[64 * 136];   // [d][i]
  __shared__ ushort eT[64 * 40];    // [d][e-local], stride 40 (80B, 16B-mult)
  __shared__ float wv[6 * 128];
  const int t = threadIdx.x;
  ushort* hb = (ushort*)(ws + WS_H);
  const ushort* w2t = (const ushort*)(ws + WS_W2T);

  #pragma unroll
  for (int k = 0; k < 4; k++) {
    int f = t + 256 * k;                 // 0..1023
    int e = f >> 5, iq = f & 31;
    float4 v = *(const float4*)&X[(n * E_N + e0 + e) * IN_D + iq * 4];
    uint2 pk;
    pk.x = (uint)f2bf(v.x) | ((uint)f2bf(v.y) << 16);
    pk.y = (uint)f2bf(v.z) | ((uint)f2bf(v.w) << 16);
    *(uint2*)&A[e * 136 + iq * 4] = pk;
  }
  #pragma unroll
  for (int k = 0; k < 4; k++) {
    int f = t + 256 * k;                 // 0..1023
    int d = f >> 4, iq8 = f & 15;
    *(uint4*)&BT[d * 136 + iq8 * 8] = *(const uint4*)&w2t[d * 128 + iq8 * 8];
  }
  #pragma unroll
  for (int k = 0; k < 3; k++) {
    int idx = t + 256 * k;               // 768
    int row = idx >> 7, i = idx & 127;
    wv[idx] = (row < 3) ? ws[WS_WSRC + row * 4096 + n * 128 + i]
                        : ws[WS_WDST + (row - 3) * 4096 + n * 128 + i];
  }
  __syncthreads();

  const int w = t >> 6, lane = t & 63;
  const int m15 = lane & 15, quad = lane >> 4;
  const int msub = w & 1, dhalf = w >> 1;

  float4x acc2[2];
  acc2[0] = (float4x)(0.f); acc2[1] = (float4x)(0.f);
  #pragma unroll
  for (int ks = 0; ks < 4; ks++) {
    short8x af = *(const short8x*)&A[(msub * 16 + m15) * 136 + ks * 32 + quad * 8];
    #pragma unroll
    for (int dd = 0; dd < 2; dd++) {
      short8x bfv = *(const short8x*)&BT[((dhalf * 2 + dd) * 16 + m15) * 136 + ks * 32 + quad * 8];
      acc2[dd] = __builtin_amdgcn_mfma_f32_16x16x32_bf16(af, bfv, acc2[dd], 0, 0, 0);
    }
  }

  if (t < 192) {
    const int e = t / 6, q = t % 6;
    float acc = 0.f;
    #pragma unroll
    for (int i8 = 0; i8 < 16; i8++) {
      uint4 pk = *(const uint4*)&A[e * 136 + i8 * 8];
      const float* wp = &wv[q * 128 + i8 * 8];
      acc += bf2f((ushort)(pk.x & 0xffff)) * wp[0];
      acc += bf2f((ushort)(pk.x >> 16))    * wp[1];
      acc += bf2f((ushort)(pk.y & 0xffff)) * wp[2];
      acc += bf2f((ushort)(pk.y >> 16))    * wp[3];
      acc += bf2f((ushort)(pk.z & 0xffff)) * wp[4];
      acc += bf2f((ushort)(pk.z >> 16))    * wp[5];
      acc += bf2f((ushort)(pk.w & 0xffff)) * wp[6];
      acc += bf2f((ushort)(pk.w >> 16))    * wp[7];
    }
    if (q < 3) ws[WS_SSRC + q * 16384 + n * 512 + e0 + e] = acc;
    else       ws[WS_SDST + (q - 3) * 16384 + n * 512 + e0 + e] = acc;
  }

  // epilogue: C (e=quad*4+rg row, d col) * mask -> eT[d][e] bf16
  float mv[4];
  #pragma unroll
  for (int rg = 0; rg < 4; rg++)
    mv[rg] = mask[n * E_N + e0 + msub * 16 + quad * 4 + rg];
  #pragma unroll
  for (int dd = 0; dd < 2; dd++) {
    int dRow = (dhalf * 2 + dd) * 16 + m15;
    #pragma unroll
    for (int rg = 0; rg < 4; rg++) {
      int e = msub * 16 + quad * 4 + rg;
      eT[dRow * 40 + e] = f2bf(acc2[dd][rg] * mv[rg]);
    }
  }
  __syncthreads();

  // hTg[n][d][e0+e]: one uint4 (8 e) per thread, sector-coalesced
  {
    int d = t >> 2, e8 = t & 3;
    *(uint4*)&hb[(n * 64 + d) * 512 + e0 + e8 * 8] =
        *(const uint4*)&eT[d * 40 + e8 * 8];
  }
}

// ---------------------------------------------------------------------------
// K3: per-row softmax denom + 2-bit adj pack (4096 blocks, wave-per-row).
// ---------------------------------------------------------------------------
__global__ __launch_bounds__(256) void k3_rowstats(const int* __restrict__ adj,
                                                   float* __restrict__ ws) {
  const int n  = blockIdx.x >> 7;
  const int ib = blockIdx.x & 127;
  __shared__ float sd[3 * 512];
  const int t = threadIdx.x;
  ushort* adj2 = (ushort*)(ws + WS_ADJ2);

  #pragma unroll
  for (int k = 0; k < 6; k++) {
    int idx = t + 256 * k;
    sd[idx] = ws[WS_SDST + (idx >> 9) * 16384 + n * 512 + (idx & 511)];
  }
  __syncthreads();

  const int wave = t >> 6, lane = t & 63;
  const int i = ib * 4 + wave;
  const float s0 = ws[WS_SSRC + 0 * 16384 + n * 512 + i];
  const float s1 = ws[WS_SSRC + 1 * 16384 + n * 512 + i];
  const float s2 = ws[WS_SSRC + 2 * 16384 + n * 512 + i];
  const int* arow = &adj[(n * E_N + i) * E_N];

  float sum = 0.f;
  uint pack = 0;
  #pragma unroll
  for (int b = 0; b < 8; b++) {
    int j = b * 64 + lane;
    int a = arow[j];
    pack |= (uint)(a & 3) << (2 * b);
    if (a > 0) {
      float s = (a == 1) ? s0 : (a == 2 ? s1 : s2);
      float v = s + sd[(a - 1) * 512 + j];
      v = v > 0.f ? v : 0.2f * v;
      sum += __expf(v);
    }
  }
  #pragma unroll
  for (int off = 32; off >= 1; off >>= 1) sum += __shfl_xor(sum, off, 64);
  if (lane == 0) ws[WS_RINV + n * 512 + i] = 1.f / sum;
  adj2[(n * E_N + i) * 64 + lane] = (ushort)pack;   // 128 B/wave coalesced
}

// ---------------------------------------------------------------------------
// K4: out[n,j,d] = sum_i coef[n,i,j]*h[n,i,d] via MFMA, single pass over i.
// grid 32*16 (n, j-tile 32), block 256 = 4 waves. 4 i-chunks of 128.
// hT staged via straight coalesced uint4 copies from transposed hTg
// (no transpose, no scalar LDS writes); B-frags read b128 from LDS
// (stride 136 -> 2-way bank aliasing = free).
// ---------------------------------------------------------------------------
__global__ __launch_bounds__(256) void k4_out(float* __restrict__ ws,
                                              float* __restrict__ out) {
  const int n  = blockIdx.x >> 4;
  const int j0 = (blockIdx.x & 15) << 5;
  __shared__ ushort cT[32 * 136];
  __shared__ ushort hT[64 * 136];   // [d][i-local]
  __shared__ ushort aS[128 * 64];   // adj2 tile [i-local][u]
  __shared__ float sdT[3 * 32];
  __shared__ float ssT[3 * 128];
  __shared__ float riT[128];
  const int t = threadIdx.x;
  const ushort* hb = (const ushort*)(ws + WS_H);
  const ushort* adj2 = (const ushort*)(ws + WS_ADJ2);

  if (t < 96) sdT[t] = ws[WS_SDST + (t >> 5) * 16384 + n * 512 + j0 + (t & 31)];

  const int w = t >> 6, lane = t & 63;
  const int m15 = lane & 15, quad = lane >> 4;
  const int msub = w & 1, dhalf = w >> 1;
  const int c   = t & 31;            // j-local col (coef phase)
  const int rpb = t >> 5;            // 0..7 row-pair base
  const int u     = (j0 & 63) + c;   // ushort index within adj2 row
  const int shift = 2 * (j0 >> 6);   // bit position (block-uniform)

  float4x acc[2];
  acc[0] = (float4x)(0.f); acc[1] = (float4x)(0.f);

  for (int it = 0; it < 4; it++) {
    const int i0 = it << 7;

    // hT: 8192 ushorts = 1024 uint4, coalesced both sides (rows contiguous in i)
    #pragma unroll
    for (int k = 0; k < 4; k++) {
      int f = t + 256 * k;               // 0..1023
      int d = f >> 4, i16 = f & 15;
      *(uint4*)&hT[d * 136 + i16 * 8] =
          *(const uint4*)&hb[(n * 64 + d) * 512 + i0 + i16 * 8];
    }
    // adj2 tile: 8192 ushorts = 1024 uint4, coalesced
    #pragma unroll
    for (int k = 0; k < 4; k++) {
      int f = t + 256 * k;               // 0..1023
      int r = f >> 3, c8 = f & 7;
      *(uint4*)&aS[r * 64 + c8 * 8] =
          *(const uint4*)&adj2[(size_t)(n * E_N + i0 + r) * 64 + c8 * 8];
    }
    // riT/ssT: 512 floats
    #pragma unroll
    for (int k = 0; k < 2; k++) {
      int idx = t + 256 * k;
      if (idx < 128) riT[idx] = ws[WS_RINV + n * 512 + i0 + idx];
      else {
        int j2 = idx - 128;
        ssT[j2] = ws[WS_SSRC + (j2 >> 7) * 16384 + n * 512 + i0 + (j2 & 127)];
      }
    }
    __syncthreads();

    // coef -> bf16 pairs -> cT[j][i]; adj codes from LDS aS
    #pragma unroll
    for (int k = 0; k < 8; k++) {
      int r0 = 2 * (rpb + 8 * k);
      uint pack = 0;
      int a = (aS[r0 * 64 + u] >> shift) & 3;
      if (a > 0) {
        float v = ssT[(a - 1) * 128 + r0] + sdT[(a - 1) * 32 + c];
        v = v > 0.f ? v : 0.2f * v;
        pack = f2bf(__expf(v) * riT[r0]);
      }
      a = (aS[(r0 + 1) * 64 + u] >> shift) & 3;
      if (a > 0) {
        float v = ssT[(a - 1) * 128 + r0 + 1] + sdT[(a - 1) * 32 + c];
        v = v > 0.f ? v : 0.2f * v;
        pack |= (uint)f2bf(__expf(v) * riT[r0 + 1]) << 16;
      }
      *(uint*)&cT[c * 136 + r0] = pack;
    }
    __syncthreads();

    #pragma unroll
    for (int ks = 0; ks < 4; ks++) {
      short8x af = *(const short8x*)&cT[(msub * 16 + m15) * 136 + ks * 32 + quad * 8];
      #pragma unroll
      for (int dd = 0; dd < 2; dd++) {
        short8x bfv = *(const short8x*)&hT[((dhalf * 2 + dd) * 16 + m15) * 136 + ks * 32 + quad * 8];
        acc[dd] = __builtin_amdgcn_mfma_f32_16x16x32_bf16(af, bfv, acc[dd], 0, 0, 0);
      }
    }
    __syncthreads();
  }

  #pragma unroll
  for (int dd = 0; dd < 2; dd++)
    #pragma unroll
    for (int rg = 0; rg < 4; rg++) {
      int j = j0 + msub * 16 + quad * 4 + rg;
      out[(n * E_N + j) * 64 + (dhalf * 2 + dd) * 16 + m15] = acc[dd][rg];
    }
}

extern "C" void kernel_launch(void* const* d_in, const int* in_sizes, int n_in,
                              void* d_out, int out_size, void* d_ws, size_t ws_size,
                              hipStream_t stream) {
  fp input_state  = (fp)d_in[0];
  const int* adj  = (const int*)d_in[1];
  fp query_vec    = (fp)d_in[2];
  fp node_mask    = (fp)d_in[3];
  fp W_type       = (fp)d_in[4];
  fp a_type       = (fp)d_in[5];
  fp qattn_W1     = (fp)d_in[6];
  fp qattn_W2     = (fp)d_in[7];
  float* out = (float*)d_out;
  float* ws  = (float*)d_ws;

  k1_qgate<<<96, 128, 0, stream>>>(query_vec, W_type, a_type, qattn_W1, qattn_W2, ws);
  k2_h_s<<<512, 256, 0, stream>>>(input_state, node_mask, ws);
  k3_rowstats<<<32 * 128, 256, 0, stream>>>(adj, ws);
  k4_out<<<32 * 16, 256, 0, stream>>>(ws, out);
}